// Round 3
// baseline (146.159 us; speedup 1.0000x reference)
//
#include <hip/hip_runtime.h>
#include <math.h>

#define NB 8192
#define NC 128
#define NJS 8          // j-slices (grid.y)
#define JPT 8          // j-tiles of 128 per block = (8192/128)/NJS

typedef short v8s __attribute__((ext_vector_type(8)));   // 8 bf16 (16 B)
typedef float v4f __attribute__((ext_vector_type(4)));

// fp32 -> bf16 round-to-nearest-even, returned in low 16 bits
__device__ inline unsigned bf16rne(float f) {
    unsigned u = __float_as_uint(f);
    return (u + 0x7fffu + ((u >> 16) & 1u)) >> 16;
}

// ---------------------------------------------------------------- prep:
// per row: bf16 cast (packed), sum-of-squares, CE term; init gmax/gmin/cnt.
__global__ __launch_bounds__(256) void k_prep(const float* __restrict__ x,
                                              const int* __restrict__ tgt,
                                              unsigned* __restrict__ xb,   // NB*64 uints (2 bf16 each)
                                              float* __restrict__ sq,
                                              float* __restrict__ ce,
                                              unsigned* __restrict__ gmax,
                                              unsigned* __restrict__ gmin,
                                              unsigned* __restrict__ cnt) {
    int row = blockIdx.x * 4 + (threadIdx.x >> 6);
    int l = threadIdx.x & 63;
    float2 v = ((const float2*)(x + row * NC))[l];
    xb[row * 64 + l] = bf16rne(v.x) | (bf16rne(v.y) << 16);
    float ss = fmaf(v.x, v.x, v.y * v.y);
    float mx = fmaxf(v.x, v.y);
#pragma unroll
    for (int off = 32; off; off >>= 1) {
        ss += __shfl_xor(ss, off);
        mx = fmaxf(mx, __shfl_xor(mx, off));
    }
    float es = expf(v.x - mx) + expf(v.y - mx);
#pragma unroll
    for (int off = 32; off; off >>= 1) es += __shfl_xor(es, off);
    if (l == 0) {
        sq[row] = ss;
        ce[row] = mx + logf(es) - x[row * NC + tgt[row]];
        gmax[row] = 0u;
        gmin[row] = 0x7f800000u;   // +inf
    }
    if (blockIdx.x == 0 && threadIdx.x == 0) *cnt = 0u;
}

// ---------------------------------------------------------------- triplet:
// bf16 MFMA GEMM, A in registers, B double-buffered in LDS with early-issue
// async prefetch; fused hardest-pos/neg reduction; fused last-block tail.
// B LDS tiles chunk-XOR-swizzled on the GLOBAL source address (global_load_lds
// LDS destination is fixed wave-base + lane*16).
__global__ __launch_bounds__(256, 2) void k_trip(const unsigned* __restrict__ xb,
                                                 const int* __restrict__ tgt,
                                                 const float* __restrict__ sq,
                                                 unsigned* __restrict__ gmax,
                                                 unsigned* __restrict__ gmin,
                                                 const float* __restrict__ ce,
                                                 unsigned* __restrict__ cnt,
                                                 float* __restrict__ out) {
    __shared__ short Bs[2][128 * 128];   // 2 x 32 KB
    __shared__ float sh[4], sc2[4];
    __shared__ unsigned lastFlag;

    const int tid = threadIdx.x;
    const int lane = tid & 63;
    const int w = tid >> 6;           // wave 0..3
    const int rh = w >> 1;            // row half (64 rows)
    const int ch = w & 1;             // col half
    const int i0 = blockIdx.x * 128;
    const int jbase = blockIdx.y * JPT * 128;
    const int m = lane & 15;
    const int quad = lane >> 4;

    // ---- issue B tile 0 stage (async) ----
#pragma unroll
    for (int c = 0; c < 8; ++c) {
        int L = w * 512 + c * 64 + lane;          // chunk index 0..2047
        int r = L >> 4, cc = L & 15;
        const unsigned* src = xb + (size_t)(jbase + r) * 64 + ((cc ^ (r & 7)) << 2);
        __builtin_amdgcn_global_load_lds(
            (const __attribute__((address_space(1))) unsigned*)src,
            (__attribute__((address_space(3))) unsigned*)(&Bs[0][0] + (w * 512 + c * 64) * 8),
            16, 0, 0);
    }

    // ---- A fragments straight into registers (once per block) ----
    v8s a[4][4];
#pragma unroll
    for (int tm = 0; tm < 4; ++tm)
#pragma unroll
        for (int ks = 0; ks < 4; ++ks) {
            int row = i0 + rh * 64 + tm * 16 + m;
            a[tm][ks] = *(const v8s*)(xb + (size_t)row * 64 + (ks * 4 + quad) * 4);
        }

    // ---- anchor targets for this lane's output rows ----
    int ti[4][4];
#pragma unroll
    for (int tm = 0; tm < 4; ++tm)
#pragma unroll
        for (int r = 0; r < 4; ++r)
            ti[tm][r] = tgt[i0 + rh * 64 + tm * 16 + quad * 4 + r];

    float mp[4][4], mn[4][4];
#pragma unroll
    for (int tm = 0; tm < 4; ++tm)
#pragma unroll
        for (int r = 0; r < 4; ++r) { mp[tm][r] = -3.0e38f; mn[tm][r] = 3.0e38f; }

    __syncthreads();   // drains vmcnt: B0 + A visible

    for (int jt = 0; jt < JPT; ++jt) {
        int j0 = jbase + jt * 128;
        const short* Bcur = &Bs[jt & 1][0];

        // ---- early-issue prefetch of NEXT B tile into the other buffer ----
        if (jt + 1 < JPT) {
            int jn = j0 + 128;
            short* Bnxt = &Bs[(jt + 1) & 1][0];
#pragma unroll
            for (int c = 0; c < 8; ++c) {
                int L = w * 512 + c * 64 + lane;
                int r = L >> 4, cc = L & 15;
                const unsigned* src = xb + (size_t)(jn + r) * 64 + ((cc ^ (r & 7)) << 2);
                __builtin_amdgcn_global_load_lds(
                    (const __attribute__((address_space(1))) unsigned*)src,
                    (__attribute__((address_space(3))) unsigned*)(Bnxt + (w * 512 + c * 64) * 8),
                    16, 0, 0);
            }
        }

        // ---- column metadata for this tile (hoisted so vmcnt hides) ----
        float sqj[4]; int tj[4];
#pragma unroll
        for (int tn = 0; tn < 4; ++tn) {
            int col = j0 + ch * 64 + tn * 16 + m;
            sqj[tn] = sq[col];
            tj[tn] = tgt[col];
        }

        // ---- MFMA over K=128 ----
        v4f acc[4][4];
        v4f z = {0.0f, 0.0f, 0.0f, 0.0f};
#pragma unroll
        for (int tm = 0; tm < 4; ++tm)
#pragma unroll
            for (int tn = 0; tn < 4; ++tn) acc[tm][tn] = z;

#pragma unroll
        for (int ks = 0; ks < 4; ++ks) {
            v8s b[4];
            int q = ks * 4 + quad;               // 16-B k-chunk index
#pragma unroll
            for (int tn = 0; tn < 4; ++tn) {
                int col = ch * 64 + tn * 16 + m;
                b[tn] = *(const v8s*)(Bcur + col * 128 + ((q ^ (col & 7)) << 3));
            }
#pragma unroll
            for (int tm = 0; tm < 4; ++tm)
#pragma unroll
                for (int tn = 0; tn < 4; ++tn)
                    acc[tm][tn] = __builtin_amdgcn_mfma_f32_16x16x32_bf16(
                        a[tm][ks], b[tn], acc[tm][tn], 0, 0, 0);
        }

        // ---- fused epilogue: v = sqj - 2*dot (sqi added at the end) ----
#pragma unroll
        for (int tn = 0; tn < 4; ++tn) {
#pragma unroll
            for (int tm = 0; tm < 4; ++tm)
#pragma unroll
                for (int r = 0; r < 4; ++r) {
                    float v = fmaf(-2.0f, acc[tm][tn][r], sqj[tn]);
                    bool pos = (tj[tn] == ti[tm][r]);
                    mp[tm][r] = fmaxf(mp[tm][r], pos ? v : -3.0e38f);
                    mn[tm][r] = fminf(mn[tm][r], pos ? 3.0e38f : v);
                }
        }

        __syncthreads();   // end-of-iter: prefetch had the whole compute to land
    }

    // ---- reduce across the 16 lanes (lane&15) sharing each output row ----
#pragma unroll
    for (int off = 1; off < 16; off <<= 1) {
#pragma unroll
        for (int tm = 0; tm < 4; ++tm)
#pragma unroll
            for (int r = 0; r < 4; ++r) {
                mp[tm][r] = fmaxf(mp[tm][r], __shfl_xor(mp[tm][r], off));
                mn[tm][r] = fminf(mn[tm][r], __shfl_xor(mn[tm][r], off));
            }
    }
    if (m == 0) {
#pragma unroll
        for (int tm = 0; tm < 4; ++tm)
#pragma unroll
            for (int r = 0; r < 4; ++r) {
                int i = i0 + rh * 64 + tm * 16 + quad * 4 + r;
                float s = sq[i];
                float d2p = fmaxf(s + mp[tm][r], 0.0f);
                float d2n = fmaxf(s + mn[tm][r], 0.0f);
                atomicMax(gmax + i, __float_as_uint(d2p));   // >=0: uint order == float order
                atomicMin(gmin + i, __float_as_uint(d2n));
            }
    }

    // ---- last-block-done fused tail ----
    __threadfence();
    if (tid == 0) {
        unsigned prev = atomicAdd(cnt, 1u);
        lastFlag = (prev == (unsigned)(gridDim.x * gridDim.y - 1));
    }
    __syncthreads();
    if (!lastFlag) return;

    float hs = 0.0f, cs = 0.0f;
    for (int i = tid; i < NB; i += 256) {
        // atomic no-op RMWs: coherent read-back of other blocks' results
        unsigned up = atomicMax(gmax + i, 0u);
        unsigned un = atomicMin(gmin + i, 0x7f800000u);
        float ap = sqrtf(fmaxf(__uint_as_float(up), 1e-12f));
        float an = sqrtf(fmaxf(__uint_as_float(un), 1e-12f));
        hs += fmaxf(ap - an + 0.3f, 0.0f);
        cs += ce[i];
    }
#pragma unroll
    for (int off = 32; off; off >>= 1) {
        hs += __shfl_xor(hs, off);
        cs += __shfl_xor(cs, off);
    }
    if (lane == 0) { sh[w] = hs; sc2[w] = cs; }
    __syncthreads();
    if (tid == 0) {
        double H = 0.0, Cs = 0.0;
        for (int k = 0; k < 4; ++k) { H += sh[k]; Cs += sc2[k]; }
        const double E = 2.71828182845904523536;
        const double TAU = log(128.0);
        const double LAMd = 0.25;
        double l = H / (double)NB;
        double cev = Cs / (double)NB;
        double y = 0.5 * fmax(-2.0 / E, (l - TAU) / LAMd);
        double p = sqrt(fmax(2.0 * (E * y + 1.0), 0.0));
        double wn = -1.0 + p - p * p / 3.0 + (11.0 / 72.0) * p * p * p;
        double wlw = (y < 0.0) ? wn : log1p(fmax(y, 0.0));
#pragma unroll
        for (int it = 0; it < 10; ++it) {
            double ew = exp(wlw);
            double f = wlw * ew - y;
            double wp1 = wlw + 1.0;
            wlw = wlw - f / (ew * wp1 - (wlw + 2.0) * f / (2.0 * wp1));
        }
        double sigma = exp(-wlw);
        double lg = log(sigma);
        double loss = (cev - TAU) * sigma + LAMd * lg * lg;
        out[0] = (float)(loss / (double)NB);
    }
}

// ---------------------------------------------------------------- launcher
extern "C" void kernel_launch(void* const* d_in, const int* in_sizes, int n_in,
                              void* d_out, int out_size, void* d_ws, size_t ws_size,
                              hipStream_t stream) {
    const float* x = (const float*)d_in[0];
    const int* tgt = (const int*)d_in[1];
    float* out = (float*)d_out;

    // ws: xb (NB*64 u32 = 2 MB) | sq | ce | gmax | gmin | cnt
    unsigned* xb = (unsigned*)d_ws;
    float* sq = (float*)(xb + (size_t)NB * 64);
    float* ce = sq + NB;
    unsigned* gmax = (unsigned*)(ce + NB);
    unsigned* gmin = gmax + NB;
    unsigned* cnt = gmin + NB;

    k_prep<<<NB / 4, 256, 0, stream>>>(x, tgt, xb, sq, ce, gmax, gmin, cnt);
    dim3 grid(NB / 128, NJS);
    k_trip<<<grid, 256, 0, stream>>>(xb, tgt, sq, gmax, gmin, ce, cnt, out);
}

// Round 4
// 112.987 us; speedup vs baseline: 1.2936x; 1.2936x over previous
//
#include <hip/hip_runtime.h>
#include <math.h>

#define NB 8192
#define NC 128
#define NJS 8          // j-slices (grid.y)
#define JPT 8          // j-tiles of 128 per block = (8192/128)/NJS

typedef short v8s __attribute__((ext_vector_type(8)));   // 8 bf16 (16 B)
typedef float v4f __attribute__((ext_vector_type(4)));

// fp32 -> bf16 round-to-nearest-even, returned in low 16 bits
__device__ inline unsigned bf16rne(float f) {
    unsigned u = __float_as_uint(f);
    return (u + 0x7fffu + ((u >> 16) & 1u)) >> 16;
}

// ---------------------------------------------------------------- prep:
// per row: bf16 cast (packed), sum-of-squares, CE term.
__global__ __launch_bounds__(256) void k_prep(const float* __restrict__ x,
                                              const int* __restrict__ tgt,
                                              unsigned* __restrict__ xb,   // NB*64 uints (2 bf16 each)
                                              float* __restrict__ sq,
                                              float* __restrict__ ce) {
    int row = blockIdx.x * 4 + (threadIdx.x >> 6);
    int l = threadIdx.x & 63;
    float2 v = ((const float2*)(x + row * NC))[l];
    xb[row * 64 + l] = bf16rne(v.x) | (bf16rne(v.y) << 16);
    float ss = fmaf(v.x, v.x, v.y * v.y);
    float mx = fmaxf(v.x, v.y);
#pragma unroll
    for (int off = 32; off; off >>= 1) {
        ss += __shfl_xor(ss, off);
        mx = fmaxf(mx, __shfl_xor(mx, off));
    }
    float es = expf(v.x - mx) + expf(v.y - mx);
#pragma unroll
    for (int off = 32; off; off >>= 1) es += __shfl_xor(es, off);
    if (l == 0) {
        sq[row] = ss;
        ce[row] = mx + logf(es) - x[row * NC + tgt[row]];
    }
}

// ---------------------------------------------------------------- triplet:
// bf16 MFMA GEMM, A in registers, B double-buffered in LDS with early-issue
// async prefetch; fused hardest-pos/neg reduction. NO atomics, NO fences:
// each (block, wave) owns a disjoint (slice, row-range) of the partial
// arrays and writes with plain stores. B LDS tiles chunk-XOR-swizzled on
// the GLOBAL source address (global_load_lds LDS dest is wave-base+lane*16).
__global__ __launch_bounds__(256, 2) void k_trip(const unsigned* __restrict__ xb,
                                                 const int* __restrict__ tgt,
                                                 const float* __restrict__ sq,
                                                 float* __restrict__ pmax,   // [16][NB]
                                                 float* __restrict__ pmin) { // [16][NB]
    __shared__ short Bs[2][128 * 128];   // 2 x 32 KB

    const int tid = threadIdx.x;
    const int lane = tid & 63;
    const int w = tid >> 6;           // wave 0..3
    const int rh = w >> 1;            // row half (64 rows)
    const int ch = w & 1;             // col half
    const int i0 = blockIdx.x * 128;
    const int jbase = blockIdx.y * JPT * 128;
    const int m = lane & 15;
    const int quad = lane >> 4;

    // ---- issue B tile 0 stage (async) ----
#pragma unroll
    for (int c = 0; c < 8; ++c) {
        int L = w * 512 + c * 64 + lane;          // chunk index 0..2047
        int r = L >> 4, cc = L & 15;
        const unsigned* src = xb + (size_t)(jbase + r) * 64 + ((cc ^ (r & 7)) << 2);
        __builtin_amdgcn_global_load_lds(
            (const __attribute__((address_space(1))) unsigned*)src,
            (__attribute__((address_space(3))) unsigned*)(&Bs[0][0] + (w * 512 + c * 64) * 8),
            16, 0, 0);
    }

    // ---- A fragments straight into registers (once per block) ----
    v8s a[4][4];
#pragma unroll
    for (int tm = 0; tm < 4; ++tm)
#pragma unroll
        for (int ks = 0; ks < 4; ++ks) {
            int row = i0 + rh * 64 + tm * 16 + m;
            a[tm][ks] = *(const v8s*)(xb + (size_t)row * 64 + (ks * 4 + quad) * 4);
        }

    // ---- anchor targets for this lane's output rows ----
    int ti[4][4];
#pragma unroll
    for (int tm = 0; tm < 4; ++tm)
#pragma unroll
        for (int r = 0; r < 4; ++r)
            ti[tm][r] = tgt[i0 + rh * 64 + tm * 16 + quad * 4 + r];

    float mp[4][4], mn[4][4];
#pragma unroll
    for (int tm = 0; tm < 4; ++tm)
#pragma unroll
        for (int r = 0; r < 4; ++r) { mp[tm][r] = -3.0e38f; mn[tm][r] = 3.0e38f; }

    __syncthreads();   // drains vmcnt: B0 + A visible

    for (int jt = 0; jt < JPT; ++jt) {
        int j0 = jbase + jt * 128;
        const short* Bcur = &Bs[jt & 1][0];

        // ---- early-issue prefetch of NEXT B tile into the other buffer ----
        if (jt + 1 < JPT) {
            int jn = j0 + 128;
            short* Bnxt = &Bs[(jt + 1) & 1][0];
#pragma unroll
            for (int c = 0; c < 8; ++c) {
                int L = w * 512 + c * 64 + lane;
                int r = L >> 4, cc = L & 15;
                const unsigned* src = xb + (size_t)(jn + r) * 64 + ((cc ^ (r & 7)) << 2);
                __builtin_amdgcn_global_load_lds(
                    (const __attribute__((address_space(1))) unsigned*)src,
                    (__attribute__((address_space(3))) unsigned*)(Bnxt + (w * 512 + c * 64) * 8),
                    16, 0, 0);
            }
        }

        // ---- column metadata for this tile (hoisted so latency hides) ----
        float sqj[4]; int tj[4];
#pragma unroll
        for (int tn = 0; tn < 4; ++tn) {
            int col = j0 + ch * 64 + tn * 16 + m;
            sqj[tn] = sq[col];
            tj[tn] = tgt[col];
        }

        // ---- MFMA over K=128 ----
        v4f acc[4][4];
        v4f z = {0.0f, 0.0f, 0.0f, 0.0f};
#pragma unroll
        for (int tm = 0; tm < 4; ++tm)
#pragma unroll
            for (int tn = 0; tn < 4; ++tn) acc[tm][tn] = z;

#pragma unroll
        for (int ks = 0; ks < 4; ++ks) {
            v8s b[4];
            int q = ks * 4 + quad;               // 16-B k-chunk index
#pragma unroll
            for (int tn = 0; tn < 4; ++tn) {
                int col = ch * 64 + tn * 16 + m;
                b[tn] = *(const v8s*)(Bcur + col * 128 + ((q ^ (col & 7)) << 3));
            }
#pragma unroll
            for (int tm = 0; tm < 4; ++tm)
#pragma unroll
                for (int tn = 0; tn < 4; ++tn)
                    acc[tm][tn] = __builtin_amdgcn_mfma_f32_16x16x32_bf16(
                        a[tm][ks], b[tn], acc[tm][tn], 0, 0, 0);
        }

        // ---- fused epilogue: v = sqj - 2*dot (sqi added in k_tail) ----
#pragma unroll
        for (int tn = 0; tn < 4; ++tn) {
#pragma unroll
            for (int tm = 0; tm < 4; ++tm)
#pragma unroll
                for (int r = 0; r < 4; ++r) {
                    float v = fmaf(-2.0f, acc[tm][tn][r], sqj[tn]);
                    bool pos = (tj[tn] == ti[tm][r]);
                    mp[tm][r] = fmaxf(mp[tm][r], pos ? v : -3.0e38f);
                    mn[tm][r] = fminf(mn[tm][r], pos ? 3.0e38f : v);
                }
        }

        __syncthreads();   // prefetch had the whole compute phase to land
    }

    // ---- reduce across the 16 lanes (lane&15) sharing each output row ----
#pragma unroll
    for (int off = 1; off < 16; off <<= 1) {
#pragma unroll
        for (int tm = 0; tm < 4; ++tm)
#pragma unroll
            for (int r = 0; r < 4; ++r) {
                mp[tm][r] = fmaxf(mp[tm][r], __shfl_xor(mp[tm][r], off));
                mn[tm][r] = fminf(mn[tm][r], __shfl_xor(mn[tm][r], off));
            }
    }
    // ---- plain stores to this wave's private (slice, row-range) ----
    if (m == 0) {
        int slice = blockIdx.y * 2 + ch;
        float* pm = pmax + (size_t)slice * NB + i0 + rh * 64;
        float* pn = pmin + (size_t)slice * NB + i0 + rh * 64;
#pragma unroll
        for (int tm = 0; tm < 4; ++tm)
#pragma unroll
            for (int r = 0; r < 4; ++r) {
                int rr = tm * 16 + quad * 4 + r;
                pm[rr] = mp[tm][r];
                pn[rr] = mn[tm][r];
            }
    }
}

// ---------------------------------------------------------------- tail:
// combine 16 slices, hinge, CE sum, Lambert-W scalar; single block.
__global__ __launch_bounds__(1024) void k_tail(const float* __restrict__ sq,
                                               const float* __restrict__ ce,
                                               const float* __restrict__ pmax,
                                               const float* __restrict__ pmin,
                                               float* __restrict__ out) {
    float hs = 0.0f, cs = 0.0f;
    for (int i = threadIdx.x; i < NB; i += 1024) {
        float vmax = -3.0e38f, vmin = 3.0e38f;
#pragma unroll
        for (int s = 0; s < 16; ++s) {
            vmax = fmaxf(vmax, pmax[s * NB + i]);
            vmin = fminf(vmin, pmin[s * NB + i]);
        }
        float sqi = sq[i];
        float ap = sqrtf(fmaxf(fmaxf(sqi + vmax, 0.0f), 1e-12f));
        float an = sqrtf(fmaxf(fmaxf(sqi + vmin, 0.0f), 1e-12f));
        hs += fmaxf(ap - an + 0.3f, 0.0f);
        cs += ce[i];
    }
#pragma unroll
    for (int off = 32; off; off >>= 1) {
        hs += __shfl_xor(hs, off);
        cs += __shfl_xor(cs, off);
    }
    __shared__ float sh[16], sc[16];
    int wv = threadIdx.x >> 6;
    if ((threadIdx.x & 63) == 0) { sh[wv] = hs; sc[wv] = cs; }
    __syncthreads();
    if (threadIdx.x == 0) {
        double H = 0.0, Cs = 0.0;
        for (int k = 0; k < 16; ++k) { H += sh[k]; Cs += sc[k]; }
        const double E = 2.71828182845904523536;
        const double TAU = log(128.0);
        const double LAMd = 0.25;
        double l = H / (double)NB;
        double cev = Cs / (double)NB;
        double y = 0.5 * fmax(-2.0 / E, (l - TAU) / LAMd);
        double p = sqrt(fmax(2.0 * (E * y + 1.0), 0.0));
        double wn = -1.0 + p - p * p / 3.0 + (11.0 / 72.0) * p * p * p;
        double wlw = (y < 0.0) ? wn : log1p(fmax(y, 0.0));
#pragma unroll
        for (int it = 0; it < 10; ++it) {
            double ew = exp(wlw);
            double f = wlw * ew - y;
            double wp1 = wlw + 1.0;
            wlw = wlw - f / (ew * wp1 - (wlw + 2.0) * f / (2.0 * wp1));
        }
        double sigma = exp(-wlw);
        double lg = log(sigma);
        double loss = (cev - TAU) * sigma + LAMd * lg * lg;
        out[0] = (float)(loss / (double)NB);
    }
}

// ---------------------------------------------------------------- launcher
extern "C" void kernel_launch(void* const* d_in, const int* in_sizes, int n_in,
                              void* d_out, int out_size, void* d_ws, size_t ws_size,
                              hipStream_t stream) {
    const float* x = (const float*)d_in[0];
    const int* tgt = (const int*)d_in[1];
    float* out = (float*)d_out;

    // ws: xb (NB*64 u32 = 2 MB) | sq | ce | pmax[16*NB] | pmin[16*NB]
    unsigned* xb = (unsigned*)d_ws;
    float* sq = (float*)(xb + (size_t)NB * 64);
    float* ce = sq + NB;
    float* pmax = ce + NB;
    float* pmin = pmax + (size_t)16 * NB;

    k_prep<<<NB / 4, 256, 0, stream>>>(x, tgt, xb, sq, ce);
    dim3 grid(NB / 128, NJS);
    k_trip<<<grid, 256, 0, stream>>>(xb, tgt, sq, pmax, pmin);
    k_tail<<<1, 1024, 0, stream>>>(sq, ce, pmax, pmin, out);
}